// Round 4
// baseline (4125.882 us; speedup 1.0000x reference)
//
#include <hip/hip_runtime.h>

typedef _Float16 f16_t;
typedef _Float16 f16x8 __attribute__((ext_vector_type(8)));
typedef _Float16 f16x4 __attribute__((ext_vector_type(4)));
typedef float    f32x4 __attribute__((ext_vector_type(4)));

#define LAYERS 12
#define HDIM   256
#define CDIM   256

// packed-weight workspace layout (f16 elements)
#define W0P_OFF 0
#define WCP_OFF 8192
#define WRP_OFF 73728
#define WRP_SZ  65536
#define WFP_OFF 335872
#define LSTRIDE 532480
#define PACK_TOTAL (LAYERS * LSTRIDE)
#define CTX_BYTE ((size_t)PACK_TOTAL * 2)

// ---------------------------------------------------------------------------
// Prepass: mask + cast + pack weights into MFMA B-fragment order.
// B-frag for 16x16x32: element (n = lane&15, k = quad*8+j) of tile (nt,kt)
// stored at ((nt*KT + kt)*64 + lane)*8 + j  -> one 16B load per lane.
// (byte-identical to the round-2 pack kernel)
// ---------------------------------------------------------------------------
__global__ __launch_bounds__(256) void nsf_pack(
    const float* __restrict__ W0, const float* __restrict__ Wc,
    const float* __restrict__ Wr, const float* __restrict__ Wf,
    f16_t* __restrict__ wp)
{
    int e = blockIdx.x * 256 + threadIdx.x;
    if (e >= PACK_TOTAL) return;
    int l = e / LSTRIDE;
    int r = e - l * LSTRIDE;
    float v = 0.f;
    if (r < WCP_OFF) {                       // W0p: N=256, K=32 (padded from 16), masked m0
        int t = r >> 9, lane = (r >> 3) & 63, j = r & 7;
        int n = t * 16 + (lane & 15);
        int k = (lane >> 4) * 8 + j;
        if (k < 16 && (n % 15 + 1) >= (k + 1))
            v = W0[(l * HDIM + n) * 16 + k];
    } else if (r < WRP_OFF) {                // Wcp: N=256, K=256, no mask
        int q = r - WCP_OFF;
        int t = q >> 9, lane = (q >> 3) & 63, j = q & 7;
        int n = (t >> 3) * 16 + (lane & 15);
        int k = (t & 7) * 32 + (lane >> 4) * 8 + j;
        v = Wc[(l * HDIM + n) * CDIM + k];
    } else if (r < WFP_OFF) {                // Wrp[4]: N=256, K=256, masked mh
        int q = r - WRP_OFF;
        int rr = q >> 16; q &= 65535;
        int t = q >> 9, lane = (q >> 3) & 63, j = q & 7;
        int n = (t >> 3) * 16 + (lane & 15);
        int k = (t & 7) * 32 + (lane >> 4) * 8 + j;
        if ((n % 15) >= (k % 15))
            v = Wr[(((l * 2 + (rr >> 1)) * 2 + (rr & 1)) * HDIM + n) * HDIM + k];
    } else {                                 // Wfp: N=768 (16 feats x 48, padded from 47), masked mf
        int q = r - WFP_OFF;
        int t = q >> 9, lane = (q >> 3) & 63, j = q & 7;
        int np = (t >> 3) * 16 + (lane & 15);
        int k = (t & 7) * 32 + (lane >> 4) * 8 + j;
        int f = np / 48, jj = np % 48;
        if (jj < 47 && (f + 1) > (k % 15 + 1))
            v = Wf[(l * 752 + f * 47 + jj) * HDIM + k];
    }
    wp[e] = (f16_t)v;
}

__global__ __launch_bounds__(256) void nsf_ctx16(
    const float* __restrict__ ctx, f16_t* __restrict__ c16, int n4)
{
    int i = blockIdx.x * 256 + threadIdx.x;
    if (i >= n4) return;
    float4 v = reinterpret_cast<const float4*>(ctx)[i];
    f16x4 o = { (f16_t)v.x, (f16_t)v.y, (f16_t)v.z, (f16_t)v.w };
    reinterpret_cast<f16x4*>(c16)[i] = o;
}

// ---------------------------------------------------------------------------
__device__ __forceinline__ float splus(float x) {
    return (x > 20.f) ? x : log1pf(__expf(x));
}

// prefetch kt=0 B-fragments (weights) for a 256-K gemm
__device__ __forceinline__ void prefB(f16x8 (&pre)[4], const f16_t* __restrict__ wb,
                                      int wave, int lane)
{
#pragma unroll
    for (int ni = 0; ni < 4; ++ni)
        pre[ni] = *reinterpret_cast<const f16x8*>(wb + (((wave * 4 + ni) * 8) * 64 + lane) * 8);
}

// C = A(64x256, LDS) * W^T(256x256, packed global)  accumulated into acc
__device__ __forceinline__ void gemm256(f32x4 (&acc)[4][4],
                                        const f16_t (&A)[64][264],
                                        const f16_t* __restrict__ wb,
                                        const f16x8 (&pre)[4],
                                        int wave, int lane, int quad, int l16)
{
#pragma unroll
    for (int kt = 0; kt < 8; ++kt) {
        f16x8 a[4];
#pragma unroll
        for (int mi = 0; mi < 4; ++mi)
            a[mi] = *reinterpret_cast<const f16x8*>(&A[mi * 16 + l16][kt * 32 + quad * 8]);
#pragma unroll
        for (int ni = 0; ni < 4; ++ni) {
            f16x8 b = (kt == 0) ? pre[ni]
                : *reinterpret_cast<const f16x8*>(wb + ((((wave * 4 + ni) * 8) + kt) * 64 + lane) * 8);
#pragma unroll
            for (int mi = 0; mi < 4; ++mi)
                acc[mi][ni] = __builtin_amdgcn_mfma_f32_16x16x32_f16(a[mi], b, acc[mi][ni], 0, 0, 0);
        }
    }
}

template <bool RELU>
__device__ __forceinline__ void stage_c(const f32x4 (&acc)[4][4], f16_t (&A)[64][264],
                                        int wave, int quad, int l16)
{
#pragma unroll
    for (int mi = 0; mi < 4; ++mi)
#pragma unroll
        for (int ni = 0; ni < 4; ++ni)
#pragma unroll
            for (int rr = 0; rr < 4; ++rr) {
                float v = acc[mi][ni][rr];
                if (RELU) v = fmaxf(v, 0.f);
                A[mi * 16 + quad * 4 + rr][wave * 64 + ni * 16 + l16] = (f16_t)v;
            }
}

// ---------------------------------------------------------------------------
// Persistent flow kernel: each block owns 64 batch rows across all 12 layers.
// ---------------------------------------------------------------------------
template <bool CTX16>
__global__ __launch_bounds__(256, 2) __attribute__((amdgpu_waves_per_eu(2, 2)))
void nsf_flow(
    const float* __restrict__ x_in, const float* __restrict__ ctx32,
    const f16_t* __restrict__ ctx16,
    const float* __restrict__ b0, const float* __restrict__ bc,
    const float* __restrict__ br, const float* __restrict__ bfb,
    const f16_t* __restrict__ wp,
    float* __restrict__ out, int B)
{
    __shared__ f16_t act[64][264];                              // 33792 B, A-operand buffer
    __shared__ __align__(16) unsigned char pool_[64 * 194 * 2]; // 24832 B: xstage U plds
    __shared__ float xbuf[64][16];                              // 4096 B, fp32 x state

    f16_t (*xstage)[40] = reinterpret_cast<f16_t(*)[40]>(pool_);
    f16_t (*plds)[194]  = reinterpret_cast<f16_t(*)[194]>(pool_);

    const int tid  = threadIdx.x;
    const int wave = tid >> 6, lane = tid & 63;
    const int quad = lane >> 4, l16 = lane & 15;
    const int row0 = blockIdx.x * 64;
    const int srow = tid >> 2, sfl = tid & 3;   // spline item: (row, feature%4)

    for (int i = tid; i < 64 * 16; i += 256)
        xbuf[i >> 4][i & 15] = x_in[(size_t)row0 * 16 + i];

    float ld_acc = 0.f;

#pragma unroll 1
    for (int l = 0; l < LAYERS; ++l) {
        const f16_t* wl = wp + (size_t)l * LSTRIDE;

        // prefetch W0 B-frags + Wc kt0 B-frags before the barrier (read-only weights)
        f16x8 w0pre[4], pre[4];
#pragma unroll
        for (int ni = 0; ni < 4; ++ni)
            w0pre[ni] = *reinterpret_cast<const f16x8*>(wl + W0P_OFF + ((wave * 4 + ni) * 64 + lane) * 8);
        prefB(pre, wl + WCP_OFF, wave, lane);

        __syncthreads();   // prior layer fully consumed act/plds/xbuf

        // pre-read the 4 spline inputs this thread needs (x overwritten in place later)
        float xval_c[4];
#pragma unroll
        for (int c = 0; c < 4; ++c) xval_c[c] = xbuf[srow][15 - (c * 4 + sfl)];

        // stage ctx -> act (f16)
        if (CTX16) {
#pragma unroll
            for (int it = 0; it < 8; ++it) {
                int j = it * 256 + tid;          // 2048 chunks of 16B
                int rr = j >> 5, cg = j & 31;
                f16x8 v = *reinterpret_cast<const f16x8*>(ctx16 + (size_t)(row0 + rr) * CDIM + cg * 8);
                *reinterpret_cast<f16x8*>(&act[rr][cg * 8]) = v;
            }
        } else {
            int rr = tid >> 2, cg = tid & 3;
            const float* cptr = ctx32 + (size_t)(row0 + rr) * CDIM + cg * 64;
#pragma unroll
            for (int it = 0; it < 16; ++it) {
                int its = (it + cg * 4) & 15;
                float4 v = *reinterpret_cast<const float4*>(cptr + its * 4);
                f16x4 w4 = { (f16_t)v.x, (f16_t)v.y, (f16_t)v.z, (f16_t)v.w };
                *reinterpret_cast<f16x4*>(&act[rr][cg * 64 + its * 4]) = w4;
            }
        }
        // stage flipped x (zero-padded K 16..31) -> xstage
        for (int i = tid; i < 64 * 32; i += 256) {
            int rr = i >> 5, c = i & 31;
            float v = (c < 16) ? xbuf[rr][15 - c] : 0.f;
            xstage[rr][c] = (f16_t)v;
        }
        __syncthreads();

        // ---- h = xf @ (W0*m0)^T + ctx @ Wc^T + b0 + bc ----
        f32x4 hacc[4][4];
#pragma unroll
        for (int ni = 0; ni < 4; ++ni) {
            int n = wave * 64 + ni * 16 + l16;
            float bv = b0[l * HDIM + n] + bc[l * HDIM + n];
#pragma unroll
            for (int mi = 0; mi < 4; ++mi) hacc[mi][ni] = (f32x4){bv, bv, bv, bv};
        }
        {
            f16x8 a[4];
#pragma unroll
            for (int mi = 0; mi < 4; ++mi)
                a[mi] = *reinterpret_cast<const f16x8*>(&xstage[mi * 16 + l16][quad * 8]);
#pragma unroll
            for (int ni = 0; ni < 4; ++ni) {
#pragma unroll
                for (int mi = 0; mi < 4; ++mi)
                    hacc[mi][ni] = __builtin_amdgcn_mfma_f32_16x16x32_f16(a[mi], w0pre[ni], hacc[mi][ni], 0, 0, 0);
            }
        }
        gemm256(hacc, act, wl + WCP_OFF, pre, wave, lane, quad, l16);

        // ---- 2 residual blocks ----
#pragma unroll 1
        for (int blk = 0; blk < 2; ++blk) {
            prefB(pre, wl + WRP_OFF + (size_t)(blk * 2) * WRP_SZ, wave, lane);
            __syncthreads();
            stage_c<true>(hacc, act, wave, quad, l16);
            __syncthreads();
            f32x4 tacc[4][4];
#pragma unroll
            for (int ni = 0; ni < 4; ++ni) {
                int n = wave * 64 + ni * 16 + l16;
                float bv = br[((l * 2 + blk) * 2 + 0) * HDIM + n];
#pragma unroll
                for (int mi = 0; mi < 4; ++mi) tacc[mi][ni] = (f32x4){bv, bv, bv, bv};
            }
            gemm256(tacc, act, wl + WRP_OFF + (size_t)(blk * 2) * WRP_SZ, pre, wave, lane, quad, l16);
            prefB(pre, wl + WRP_OFF + (size_t)(blk * 2 + 1) * WRP_SZ, wave, lane);
            __syncthreads();
            stage_c<true>(tacc, act, wave, quad, l16);
            __syncthreads();
#pragma unroll
            for (int ni = 0; ni < 4; ++ni) {
                int n = wave * 64 + ni * 16 + l16;
                float bv = br[((l * 2 + blk) * 2 + 1) * HDIM + n];
#pragma unroll
                for (int mi = 0; mi < 4; ++mi) tacc[mi][ni] = (f32x4){bv, bv, bv, bv};
            }
            gemm256(tacc, act, wl + WRP_OFF + (size_t)(blk * 2 + 1) * WRP_SZ, pre, wave, lane, quad, l16);
#pragma unroll
            for (int mi = 0; mi < 4; ++mi)
#pragma unroll
                for (int ni = 0; ni < 4; ++ni)
                    hacc[mi][ni] += tacc[mi][ni];
        }

        // ---- stage final h (no relu); prefetch Gf chunk0 B-frags ----
        f16x8 gpre[3], gnext[3];
#pragma unroll
        for (int ni = 0; ni < 3; ++ni)
            gpre[ni] = *reinterpret_cast<const f16x8*>(wl + WFP_OFF + (((wave * 3 + ni) * 8) * 64 + lane) * 8);
        __syncthreads();
        stage_c<false>(hacc, act, wave, quad, l16);
        __syncthreads();

        // ---- Gf in 4 chunks of 4 features (192 packed cols), fused spline ----
#pragma unroll
        for (int c = 0; c < 4; ++c) {
            f32x4 pacc[4][3];
            int fme = c * 4 + wave;   // feature this wave's 48 columns belong to
#pragma unroll
            for (int ni = 0; ni < 3; ++ni) {
                int jj = ni * 16 + l16;
                float bv = (jj < 47) ? bfb[l * 752 + fme * 47 + jj] : 0.f;
#pragma unroll
                for (int mi = 0; mi < 4; ++mi) pacc[mi][ni] = (f32x4){bv, bv, bv, bv};
            }
#pragma unroll
            for (int kt = 0; kt < 8; ++kt) {
                f16x8 a[4];
#pragma unroll
                for (int mi = 0; mi < 4; ++mi)
                    a[mi] = *reinterpret_cast<const f16x8*>(&act[mi * 16 + l16][kt * 32 + quad * 8]);
#pragma unroll
                for (int ni = 0; ni < 3; ++ni) {
                    int nt = c * 12 + wave * 3 + ni;
                    f16x8 b = (kt == 0) ? gpre[ni]
                        : *reinterpret_cast<const f16x8*>(wl + WFP_OFF + ((nt * 8 + kt) * 64 + lane) * 8);
#pragma unroll
                    for (int mi = 0; mi < 4; ++mi)
                        pacc[mi][ni] = __builtin_amdgcn_mfma_f32_16x16x32_f16(a[mi], b, pacc[mi][ni], 0, 0, 0);
                }
            }
            if (c < 3) {
#pragma unroll
                for (int ni = 0; ni < 3; ++ni)
                    gnext[ni] = *reinterpret_cast<const f16x8*>(wl + WFP_OFF + ((((c + 1) * 12 + wave * 3 + ni) * 8) * 64 + lane) * 8);
            }
            __syncthreads();   // previous chunk's spline done with plds (and xstage dead)
#pragma unroll
            for (int mi = 0; mi < 4; ++mi)
#pragma unroll
                for (int ni = 0; ni < 3; ++ni)
#pragma unroll
                    for (int rr = 0; rr < 4; ++rr)
                        plds[mi * 16 + quad * 4 + rr][wave * 48 + ni * 16 + l16] = (f16_t)pacc[mi][ni][rr];
            __syncthreads();

            // ---- RQ spline: one (row, feature) item per thread ----
            {
                int f = c * 4 + sfl;
                float xval = xval_c[c];
                const f16_t* pp = &plds[srow][sfl * 48];
                float uw[16], uh[16], ud[15];
#pragma unroll
                for (int j = 0; j < 16; ++j) {
                    uw[j] = (float)pp[j] * 0.0625f;
                    uh[j] = (float)pp[16 + j] * 0.0625f;
                }
#pragma unroll
                for (int j = 0; j < 15; ++j) ud[j] = (float)pp[32 + j];

                float mw = uw[0], mh2 = uh[0];
#pragma unroll
                for (int j = 1; j < 16; ++j) { mw = fmaxf(mw, uw[j]); mh2 = fmaxf(mh2, uh[j]); }
                float sw = 0.f, sh = 0.f;
#pragma unroll
                for (int j = 0; j < 16; ++j) {
                    uw[j] = __expf(uw[j] - mw); sw += uw[j];
                    uh[j] = __expf(uh[j] - mh2); sh += uh[j];
                }
                float rw = 0.984f / sw, rh = 0.984f / sh;
                float xc = fminf(fmaxf(xval, -3.f), 3.f);
                float cumw = 0.f, cumh = 0.f, dprev = 1.f;
                float icw = -3.f, iwv = 1.f, ich = -3.f, ihv = 1.f, dk = 1.f, dk1 = 1.f;
#pragma unroll
                for (int j = 0; j < 16; ++j) {
                    float wj = fmaf(rw, uw[j], 0.001f);
                    float hj = fmaf(rh, uh[j], 0.001f);
                    float cwn = cumw + wj, chn = cumh + hj;
                    float left  = (j == 0)  ? -3.f : fmaf(6.f, cumw, -3.f);
                    float right = (j == 15) ?  3.f : fmaf(6.f, cwn, -3.f);
                    float hl    = (j == 0)  ? -3.f : fmaf(6.f, cumh, -3.f);
                    float hr    = (j == 15) ?  3.f : fmaf(6.f, chn, -3.f);
                    float dn    = (j == 15) ? 1.f : (0.001f + splus(ud[j]));
                    if (xc >= left) {
                        icw = left; iwv = right - left;
                        ich = hl;   ihv = hr - hl;
                        dk = dprev; dk1 = dn;
                    }
                    cumw = cwn; cumh = chn; dprev = dn;
                }
                float delta = ihv / iwv;
                float th = (xc - icw) / iwv;
                float omth = 1.f - th;
                float t1m = th * omth;
                float den = delta + (dk + dk1 - 2.f * delta) * t1m;
                float y = ich + ihv * (delta * th * th + dk * t1m) / den;
                float dnum = delta * delta * (dk1 * th * th + 2.f * delta * t1m + dk * omth * omth);
                float ldv = __logf(dnum) - 2.f * __logf(den);
                bool inside = (xval >= -3.f) && (xval <= 3.f);
                xbuf[srow][f] = inside ? y : xval;
                ld_acc += inside ? ldv : 0.f;
            }
#pragma unroll
            for (int ni = 0; ni < 3; ++ni) gpre[ni] = gnext[ni];
        }
    }

    __syncthreads();
    for (int i = tid; i < 64 * 16; i += 256)
        out[(size_t)row0 * 16 + i] = xbuf[i >> 4][i & 15];
    float v = ld_acc;
    v += __shfl_xor(v, 1);
    v += __shfl_xor(v, 2);
    if ((lane & 3) == 0)
        out[(size_t)B * 16 + row0 + srow] = v;
}

// ---------------------------------------------------------------------------
extern "C" void kernel_launch(void* const* d_in, const int* in_sizes, int n_in,
                              void* d_out, int out_size, void* d_ws, size_t ws_size,
                              hipStream_t stream)
{
    const float* x   = (const float*)d_in[0];
    const float* ctx = (const float*)d_in[1];
    const float* W0  = (const float*)d_in[2];
    const float* b0  = (const float*)d_in[3];
    const float* Wc  = (const float*)d_in[4];
    const float* bc  = (const float*)d_in[5];
    const float* Wr  = (const float*)d_in[6];
    const float* br  = (const float*)d_in[7];
    const float* Wf  = (const float*)d_in[8];
    const float* bfb = (const float*)d_in[9];
    int B = in_sizes[0] / 16;

    f16_t* wp  = (f16_t*)d_ws;                     // 12.78 MB packed f16 weights
    f16_t* c16 = (f16_t*)((char*)d_ws + CTX_BYTE); // 33.5 MB f16 context (optional)
    bool useCtx16 = ws_size >= CTX_BYTE + (size_t)B * CDIM * 2;

    nsf_pack<<<(PACK_TOTAL + 255) / 256, 256, 0, stream>>>(W0, Wc, Wr, Wf, wp);
    if (useCtx16) {
        int n4 = B * CDIM / 4;
        nsf_ctx16<<<(n4 + 255) / 256, 256, 0, stream>>>(ctx, c16, n4);
        nsf_flow<true><<<B / 64, 256, 0, stream>>>(x, ctx, c16, b0, bc, br, bfb, wp, (float*)d_out, B);
    } else {
        nsf_flow<false><<<B / 64, 256, 0, stream>>>(x, ctx, c16, b0, bc, br, bfb, wp, (float*)d_out, B);
    }
}

// Round 5
// 2781.284 us; speedup vs baseline: 1.4834x; 1.4834x over previous
//
#include <hip/hip_runtime.h>

typedef _Float16 f16_t;
typedef _Float16 f16x8 __attribute__((ext_vector_type(8)));
typedef _Float16 f16x4 __attribute__((ext_vector_type(4)));
typedef float    f32x4 __attribute__((ext_vector_type(4)));

#define LAYERS 12
#define HDIM   256
#define CDIM   256
#define BROWS  32     // batch rows per block

// packed-weight workspace layout (f16 elements)
#define W0P_OFF 0
#define WCP_OFF 8192
#define WRP_OFF 73728
#define WRP_SZ  65536
#define WFP_OFF 335872
#define LSTRIDE 532480
#define PACK_TOTAL (LAYERS * LSTRIDE)
#define CTX_BYTE ((size_t)PACK_TOTAL * 2)

// ---------------------------------------------------------------------------
// Prepass: mask + cast + pack weights into MFMA B-fragment order.
// B-frag for 16x16x32: element (n = lane&15, k = quad*8+j) of tile (nt,kt)
// stored at ((nt*KT + kt)*64 + lane)*8 + j  -> one 16B load per lane.
// (byte-identical to the round-2 pack kernel)
// ---------------------------------------------------------------------------
__global__ __launch_bounds__(256) void nsf_pack(
    const float* __restrict__ W0, const float* __restrict__ Wc,
    const float* __restrict__ Wr, const float* __restrict__ Wf,
    f16_t* __restrict__ wp)
{
    int e = blockIdx.x * 256 + threadIdx.x;
    if (e >= PACK_TOTAL) return;
    int l = e / LSTRIDE;
    int r = e - l * LSTRIDE;
    float v = 0.f;
    if (r < WCP_OFF) {                       // W0p: N=256, K=32 (padded from 16), masked m0
        int t = r >> 9, lane = (r >> 3) & 63, j = r & 7;
        int n = t * 16 + (lane & 15);
        int k = (lane >> 4) * 8 + j;
        if (k < 16 && (n % 15 + 1) >= (k + 1))
            v = W0[(l * HDIM + n) * 16 + k];
    } else if (r < WRP_OFF) {                // Wcp: N=256, K=256, no mask
        int q = r - WCP_OFF;
        int t = q >> 9, lane = (q >> 3) & 63, j = q & 7;
        int n = (t >> 3) * 16 + (lane & 15);
        int k = (t & 7) * 32 + (lane >> 4) * 8 + j;
        v = Wc[(l * HDIM + n) * CDIM + k];
    } else if (r < WFP_OFF) {                // Wrp[4]: N=256, K=256, masked mh
        int q = r - WRP_OFF;
        int rr = q >> 16; q &= 65535;
        int t = q >> 9, lane = (q >> 3) & 63, j = q & 7;
        int n = (t >> 3) * 16 + (lane & 15);
        int k = (t & 7) * 32 + (lane >> 4) * 8 + j;
        if ((n % 15) >= (k % 15))
            v = Wr[(((l * 2 + (rr >> 1)) * 2 + (rr & 1)) * HDIM + n) * HDIM + k];
    } else {                                 // Wfp: N=768 (16 feats x 48, padded from 47), masked mf
        int q = r - WFP_OFF;
        int t = q >> 9, lane = (q >> 3) & 63, j = q & 7;
        int np = (t >> 3) * 16 + (lane & 15);
        int k = (t & 7) * 32 + (lane >> 4) * 8 + j;
        int f = np / 48, jj = np % 48;
        if (jj < 47 && (f + 1) > (k % 15 + 1))
            v = Wf[(l * 752 + f * 47 + jj) * HDIM + k];
    }
    wp[e] = (f16_t)v;
}

__global__ __launch_bounds__(256) void nsf_ctx16(
    const float* __restrict__ ctx, f16_t* __restrict__ c16, int n4)
{
    int i = blockIdx.x * 256 + threadIdx.x;
    if (i >= n4) return;
    float4 v = reinterpret_cast<const float4*>(ctx)[i];
    f16x4 o = { (f16_t)v.x, (f16_t)v.y, (f16_t)v.z, (f16_t)v.w };
    reinterpret_cast<f16x4*>(c16)[i] = o;
}

// ---------------------------------------------------------------------------
__device__ __forceinline__ float splus(float x) {
    return (x > 20.f) ? x : log1pf(__expf(x));
}

// C = A(32x256, LDS) * W^T(256x256, packed global)  accumulated into acc
__device__ __forceinline__ void gemm256(f32x4 (&acc)[2][4],
                                        const f16_t (&A)[BROWS][264],
                                        const f16_t* __restrict__ wb,
                                        int wave, int lane, int quad, int l16)
{
#pragma unroll
    for (int kt = 0; kt < 8; ++kt) {
        f16x8 a[2];
#pragma unroll
        for (int mi = 0; mi < 2; ++mi)
            a[mi] = *reinterpret_cast<const f16x8*>(&A[mi * 16 + l16][kt * 32 + quad * 8]);
#pragma unroll
        for (int ni = 0; ni < 4; ++ni) {
            f16x8 b = *reinterpret_cast<const f16x8*>(wb + ((((wave * 4 + ni) * 8) + kt) * 64 + lane) * 8);
#pragma unroll
            for (int mi = 0; mi < 2; ++mi)
                acc[mi][ni] = __builtin_amdgcn_mfma_f32_16x16x32_f16(a[mi], b, acc[mi][ni], 0, 0, 0);
        }
    }
}

template <bool RELU>
__device__ __forceinline__ void stage_c(const f32x4 (&acc)[2][4], f16_t (&A)[BROWS][264],
                                        int wave, int quad, int l16)
{
#pragma unroll
    for (int mi = 0; mi < 2; ++mi)
#pragma unroll
        for (int ni = 0; ni < 4; ++ni)
#pragma unroll
            for (int rr = 0; rr < 4; ++rr) {
                float v = acc[mi][ni][rr];
                if (RELU) v = fmaxf(v, 0.f);
                A[mi * 16 + quad * 4 + rr][wave * 64 + ni * 16 + l16] = (f16_t)v;
            }
}

// ---------------------------------------------------------------------------
// Persistent flow kernel: each block owns 32 batch rows across all 12 layers.
// LDS ~31.4 KB -> 4 blocks/CU (VGPR-capped at 4 waves/SIMD).
// ---------------------------------------------------------------------------
template <bool CTX16>
__global__ __launch_bounds__(256, 4)
void nsf_flow(
    const float* __restrict__ x_in, const float* __restrict__ ctx32,
    const f16_t* __restrict__ ctx16,
    const float* __restrict__ b0, const float* __restrict__ bc,
    const float* __restrict__ br, const float* __restrict__ bfb,
    const f16_t* __restrict__ wp,
    float* __restrict__ out, int B)
{
    __shared__ f16_t act[BROWS][264];                              // 16896 B
    __shared__ __align__(16) unsigned char pool_[BROWS * 194 * 2]; // 12416 B: xstage U plds
    __shared__ float xbuf[BROWS][16];                              // 2048 B

    f16_t (*xstage)[40] = reinterpret_cast<f16_t(*)[40]>(pool_);
    f16_t (*plds)[194]  = reinterpret_cast<f16_t(*)[194]>(pool_);

    const int tid  = threadIdx.x;
    const int wave = tid >> 6, lane = tid & 63;
    const int quad = lane >> 4, l16 = lane & 15;
    const int row0 = blockIdx.x * BROWS;
    const bool sact = tid < 128;                 // spline-active threads
    const int srow = (tid >> 2) & 31, sfl = tid & 3;

    for (int i = tid; i < BROWS * 16; i += 256)
        xbuf[i >> 4][i & 15] = x_in[(size_t)row0 * 16 + i];

    float ld_acc = 0.f;

#pragma unroll 1
    for (int l = 0; l < LAYERS; ++l) {
        const f16_t* wl = wp + (size_t)l * LSTRIDE;
        __syncthreads();   // prior layer fully consumed act/plds/xbuf

        // pre-read the 4 spline inputs this thread needs (x overwritten in place later)
        float xval_c[4];
        if (sact) {
#pragma unroll
            for (int c = 0; c < 4; ++c) xval_c[c] = xbuf[srow][15 - (c * 4 + sfl)];
        }

        // stage ctx -> act (f16)
        if (CTX16) {
#pragma unroll
            for (int it = 0; it < 4; ++it) {
                int j = it * 256 + tid;          // 1024 chunks of 16B
                int rr = j >> 5, cg = j & 31;
                f16x8 v = *reinterpret_cast<const f16x8*>(ctx16 + (size_t)(row0 + rr) * CDIM + cg * 8);
                *reinterpret_cast<f16x8*>(&act[rr][cg * 8]) = v;
            }
        } else {
            int rr = tid >> 3, cg = tid & 7;
            const float* cptr = ctx32 + (size_t)(row0 + rr) * CDIM + cg * 32;
#pragma unroll
            for (int it = 0; it < 8; ++it) {
                float4 v = *reinterpret_cast<const float4*>(cptr + it * 4);
                f16x4 w4 = { (f16_t)v.x, (f16_t)v.y, (f16_t)v.z, (f16_t)v.w };
                *reinterpret_cast<f16x4*>(&act[rr][cg * 32 + it * 4]) = w4;
            }
        }
        // stage flipped x (zero-padded K 16..31) -> xstage
        for (int i = tid; i < BROWS * 32; i += 256) {
            int rr = i >> 5, c = i & 31;
            float v = (c < 16) ? xbuf[rr][15 - c] : 0.f;
            xstage[rr][c] = (f16_t)v;
        }
        __syncthreads();

        // ---- h = xf @ (W0*m0)^T + ctx @ Wc^T + b0 + bc ----
        f32x4 hacc[2][4];
#pragma unroll
        for (int ni = 0; ni < 4; ++ni) {
            int n = wave * 64 + ni * 16 + l16;
            float bv = b0[l * HDIM + n] + bc[l * HDIM + n];
#pragma unroll
            for (int mi = 0; mi < 2; ++mi) hacc[mi][ni] = (f32x4){bv, bv, bv, bv};
        }
        {
            f16x8 a[2];
#pragma unroll
            for (int mi = 0; mi < 2; ++mi)
                a[mi] = *reinterpret_cast<const f16x8*>(&xstage[mi * 16 + l16][quad * 8]);
#pragma unroll
            for (int ni = 0; ni < 4; ++ni) {
                f16x8 b = *reinterpret_cast<const f16x8*>(wl + W0P_OFF + ((wave * 4 + ni) * 64 + lane) * 8);
#pragma unroll
                for (int mi = 0; mi < 2; ++mi)
                    hacc[mi][ni] = __builtin_amdgcn_mfma_f32_16x16x32_f16(a[mi], b, hacc[mi][ni], 0, 0, 0);
            }
        }
        gemm256(hacc, act, wl + WCP_OFF, wave, lane, quad, l16);

        // ---- 2 residual blocks ----
#pragma unroll 1
        for (int blk = 0; blk < 2; ++blk) {
            __syncthreads();
            stage_c<true>(hacc, act, wave, quad, l16);
            __syncthreads();
            f32x4 tacc[2][4];
#pragma unroll
            for (int ni = 0; ni < 4; ++ni) {
                int n = wave * 64 + ni * 16 + l16;
                float bv = br[((l * 2 + blk) * 2 + 0) * HDIM + n];
#pragma unroll
                for (int mi = 0; mi < 2; ++mi) tacc[mi][ni] = (f32x4){bv, bv, bv, bv};
            }
            gemm256(tacc, act, wl + WRP_OFF + (size_t)(blk * 2) * WRP_SZ, wave, lane, quad, l16);
            __syncthreads();
            stage_c<true>(tacc, act, wave, quad, l16);
            __syncthreads();
#pragma unroll
            for (int ni = 0; ni < 4; ++ni) {
                int n = wave * 64 + ni * 16 + l16;
                float bv = br[((l * 2 + blk) * 2 + 1) * HDIM + n];
#pragma unroll
                for (int mi = 0; mi < 2; ++mi) tacc[mi][ni] = (f32x4){bv, bv, bv, bv};
            }
            gemm256(tacc, act, wl + WRP_OFF + (size_t)(blk * 2 + 1) * WRP_SZ, wave, lane, quad, l16);
#pragma unroll
            for (int mi = 0; mi < 2; ++mi)
#pragma unroll
                for (int ni = 0; ni < 4; ++ni)
                    hacc[mi][ni] += tacc[mi][ni];
        }

        // ---- stage final h (no relu) ----
        __syncthreads();
        stage_c<false>(hacc, act, wave, quad, l16);
        __syncthreads();

        // ---- Gf in 4 chunks of 4 features (192 packed cols), fused spline ----
#pragma unroll
        for (int c = 0; c < 4; ++c) {
            f32x4 pacc[2][3];
            int fme = c * 4 + wave;   // feature this wave's 48 columns belong to
#pragma unroll
            for (int ni = 0; ni < 3; ++ni) {
                int jj = ni * 16 + l16;
                float bv = (jj < 47) ? bfb[l * 752 + fme * 47 + jj] : 0.f;
#pragma unroll
                for (int mi = 0; mi < 2; ++mi) pacc[mi][ni] = (f32x4){bv, bv, bv, bv};
            }
#pragma unroll
            for (int kt = 0; kt < 8; ++kt) {
                f16x8 a[2];
#pragma unroll
                for (int mi = 0; mi < 2; ++mi)
                    a[mi] = *reinterpret_cast<const f16x8*>(&act[mi * 16 + l16][kt * 32 + quad * 8]);
#pragma unroll
                for (int ni = 0; ni < 3; ++ni) {
                    int nt = c * 12 + wave * 3 + ni;
                    f16x8 b = *reinterpret_cast<const f16x8*>(wl + WFP_OFF + ((nt * 8 + kt) * 64 + lane) * 8);
#pragma unroll
                    for (int mi = 0; mi < 2; ++mi)
                        pacc[mi][ni] = __builtin_amdgcn_mfma_f32_16x16x32_f16(a[mi], b, pacc[mi][ni], 0, 0, 0);
                }
            }
            __syncthreads();   // previous chunk's spline done with plds (and xstage dead)
#pragma unroll
            for (int mi = 0; mi < 2; ++mi)
#pragma unroll
                for (int ni = 0; ni < 3; ++ni)
#pragma unroll
                    for (int rr = 0; rr < 4; ++rr)
                        plds[mi * 16 + quad * 4 + rr][wave * 48 + ni * 16 + l16] = (f16_t)pacc[mi][ni][rr];
            __syncthreads();

            // ---- RQ spline: one (row, feature) item per thread (tid<128) ----
            if (sact) {
                int f = c * 4 + sfl;
                float xval = xval_c[c];
                const f16_t* pp = &plds[srow][sfl * 48];
                float uw[16], uh[16], ud[15];
#pragma unroll
                for (int j = 0; j < 16; ++j) {
                    uw[j] = (float)pp[j] * 0.0625f;
                    uh[j] = (float)pp[16 + j] * 0.0625f;
                }
#pragma unroll
                for (int j = 0; j < 15; ++j) ud[j] = (float)pp[32 + j];

                float mw = uw[0], mh2 = uh[0];
#pragma unroll
                for (int j = 1; j < 16; ++j) { mw = fmaxf(mw, uw[j]); mh2 = fmaxf(mh2, uh[j]); }
                float sw = 0.f, sh = 0.f;
#pragma unroll
                for (int j = 0; j < 16; ++j) {
                    uw[j] = __expf(uw[j] - mw); sw += uw[j];
                    uh[j] = __expf(uh[j] - mh2); sh += uh[j];
                }
                float rw = 0.984f / sw, rh = 0.984f / sh;
                float xc = fminf(fmaxf(xval, -3.f), 3.f);
                float cumw = 0.f, cumh = 0.f, dprev = 1.f;
                float icw = -3.f, iwv = 1.f, ich = -3.f, ihv = 1.f, dk = 1.f, dk1 = 1.f;
#pragma unroll
                for (int j = 0; j < 16; ++j) {
                    float wj = fmaf(rw, uw[j], 0.001f);
                    float hj = fmaf(rh, uh[j], 0.001f);
                    float cwn = cumw + wj, chn = cumh + hj;
                    float left  = (j == 0)  ? -3.f : fmaf(6.f, cumw, -3.f);
                    float right = (j == 15) ?  3.f : fmaf(6.f, cwn, -3.f);
                    float hl    = (j == 0)  ? -3.f : fmaf(6.f, cumh, -3.f);
                    float hr    = (j == 15) ?  3.f : fmaf(6.f, chn, -3.f);
                    float dn    = (j == 15) ? 1.f : (0.001f + splus(ud[j]));
                    if (xc >= left) {
                        icw = left; iwv = right - left;
                        ich = hl;   ihv = hr - hl;
                        dk = dprev; dk1 = dn;
                    }
                    cumw = cwn; cumh = chn; dprev = dn;
                }
                float delta = ihv / iwv;
                float th = (xc - icw) / iwv;
                float omth = 1.f - th;
                float t1m = th * omth;
                float den = delta + (dk + dk1 - 2.f * delta) * t1m;
                float y = ich + ihv * (delta * th * th + dk * t1m) / den;
                float dnum = delta * delta * (dk1 * th * th + 2.f * delta * t1m + dk * omth * omth);
                float ldv = __logf(dnum) - 2.f * __logf(den);
                bool inside = (xval >= -3.f) && (xval <= 3.f);
                xbuf[srow][f] = inside ? y : xval;
                ld_acc += inside ? ldv : 0.f;
            }
        }
    }

    __syncthreads();
    for (int i = tid; i < BROWS * 16; i += 256)
        out[(size_t)row0 * 16 + i] = xbuf[i >> 4][i & 15];
    float v = ld_acc;
    v += __shfl_xor(v, 1);
    v += __shfl_xor(v, 2);
    if (sact && (lane & 3) == 0)
        out[(size_t)B * 16 + row0 + srow] = v;
}

// ---------------------------------------------------------------------------
extern "C" void kernel_launch(void* const* d_in, const int* in_sizes, int n_in,
                              void* d_out, int out_size, void* d_ws, size_t ws_size,
                              hipStream_t stream)
{
    const float* x   = (const float*)d_in[0];
    const float* ctx = (const float*)d_in[1];
    const float* W0  = (const float*)d_in[2];
    const float* b0  = (const float*)d_in[3];
    const float* Wc  = (const float*)d_in[4];
    const float* bc  = (const float*)d_in[5];
    const float* Wr  = (const float*)d_in[6];
    const float* br  = (const float*)d_in[7];
    const float* Wf  = (const float*)d_in[8];
    const float* bfb = (const float*)d_in[9];
    int B = in_sizes[0] / 16;

    f16_t* wp  = (f16_t*)d_ws;                     // 12.78 MB packed f16 weights
    f16_t* c16 = (f16_t*)((char*)d_ws + CTX_BYTE); // 33.5 MB f16 context (optional)
    bool useCtx16 = ws_size >= CTX_BYTE + (size_t)B * CDIM * 2;

    nsf_pack<<<(PACK_TOTAL + 255) / 256, 256, 0, stream>>>(W0, Wc, Wr, Wf, wp);
    if (useCtx16) {
        int n4 = B * CDIM / 4;
        nsf_ctx16<<<(n4 + 255) / 256, 256, 0, stream>>>(ctx, c16, n4);
        nsf_flow<true><<<B / BROWS, 256, 0, stream>>>(x, ctx, c16, b0, bc, br, bfb, wp, (float*)d_out, B);
    } else {
        nsf_flow<false><<<B / BROWS, 256, 0, stream>>>(x, ctx, c16, b0, bc, br, bfb, wp, (float*)d_out, B);
    }
}